// Round 1
// baseline (301.548 us; speedup 1.0000x reference)
//
#include <hip/hip_runtime.h>
#include <hip/hip_bf16.h>
#include <math.h>

typedef __attribute__((ext_vector_type(8))) short short8;
typedef __attribute__((ext_vector_type(4))) float floatx4;

#define B_ 8
#define C_ 256
#define N_ 4096

static __device__ __forceinline__ unsigned short f2bf(float f) {
  union { float f; unsigned int u; } v; v.f = f;
  unsigned int u = v.u;
  u += 0x7FFFu + ((u >> 16) & 1u);   // RNE
  return (unsigned short)(u >> 16);
}
static __device__ __forceinline__ float bf2f(unsigned short h) {
  union { unsigned int u; float f; } v; v.u = ((unsigned int)h) << 16; return v.f;
}

// ---------------- kernel 0: weight convert + ssq zero ----------------
__global__ void prep_kernel(const float* __restrict__ Wq, const float* __restrict__ Wk,
                            const float* __restrict__ Wv,
                            unsigned short* __restrict__ wqb, unsigned short* __restrict__ wkb,
                            unsigned short* __restrict__ wvb, float* __restrict__ ssq) {
  int t = blockIdx.x * 256 + threadIdx.x;
  if (t < 512) ssq[t] = 0.0f;
  if (t < 8192) { wqb[t] = f2bf(Wq[t]); wkb[t] = f2bf(Wk[t]); }
  int tv = t - 8192;
  if (tv >= 0 && tv < 65536) wvb[tv] = f2bf(Wv[tv]);
}

// ---------------- kernel 1: QKV GEMM (bf16 MFMA) ----------------
// out tiles: V (b,c,n) bf16 ; Q/K unscaled (b,n,32) bf16 ; ssq atomics
__launch_bounds__(256, 2)
__global__ void qkv_kernel(const float* __restrict__ x,
                           const unsigned short* __restrict__ wqb,
                           const unsigned short* __restrict__ wkb,
                           const unsigned short* __restrict__ wvb,
                           const float* __restrict__ bq, const float* __restrict__ bk,
                           const float* __restrict__ bv,
                           unsigned short* __restrict__ qbf, unsigned short* __restrict__ kbf,
                           unsigned short* __restrict__ vbf, float* __restrict__ ssq) {
  int b = blockIdx.x >> 6;
  int nblk = blockIdx.x & 63;
  int w = threadIdx.x >> 6, lane = threadIdx.x & 63;
  int r = lane & 15, g = lane >> 4;
  int n0 = nblk * 64 + w * 16;

  // B fragments from x: B[k=c][col=n], lane: col=r, k = g*8+j (per 32-k step)
  short8 xf[8];
  #pragma unroll
  for (int ks = 0; ks < 8; ++ks) {
    #pragma unroll
    for (int j = 0; j < 8; ++j) {
      int c = ks * 32 + g * 8 + j;
      float v = x[((size_t)(b * C_ + c) << 12) + n0 + r];
      ((unsigned short*)&xf[ks])[j] = f2bf(v);
    }
  }
  floatx4 zero = {0.f, 0.f, 0.f, 0.f};

  // ---- V tiles (16 of them) ----
  #pragma unroll 1
  for (int ot = 0; ot < 16; ++ot) {
    floatx4 acc = zero;
    #pragma unroll
    for (int ks = 0; ks < 8; ++ks) {
      short8 af = *(const short8*)&wvb[(ot * 16 + r) * 256 + ks * 32 + g * 8];
      acc = __builtin_amdgcn_mfma_f32_16x16x32_bf16(af, xf[ks], acc, 0, 0, 0);
    }
    #pragma unroll
    for (int rr = 0; rr < 4; ++rr) {
      int oc = ot * 16 + g * 4 + rr;
      vbf[((size_t)(b * C_ + oc) << 12) + n0 + r] = f2bf(acc[rr] + bv[oc]);
    }
  }
  // ---- Q then K (2 tiles each) ----
  #pragma unroll 1
  for (int qk = 0; qk < 2; ++qk) {
    const unsigned short* wb = qk ? wkb : wqb;
    const float* bias = qk ? bk : bq;
    unsigned short* dst = qk ? kbf : qbf;
    int sbase = qk ? 256 : 0;
    #pragma unroll
    for (int ot = 0; ot < 2; ++ot) {
      floatx4 acc = zero;
      #pragma unroll
      for (int ks = 0; ks < 8; ++ks) {
        short8 af = *(const short8*)&wb[(ot * 16 + r) * 256 + ks * 32 + g * 8];
        acc = __builtin_amdgcn_mfma_f32_16x16x32_bf16(af, xf[ks], acc, 0, 0, 0);
      }
      #pragma unroll
      for (int rr = 0; rr < 4; ++rr) {
        int oc = ot * 16 + g * 4 + rr;
        float val = acc[rr] + bias[oc];
        dst[(size_t)(b * N_ + n0 + r) * 32 + oc] = f2bf(val);
        float s = val * val;               // reduce over the 16 n (lanes r)
        s += __shfl_xor(s, 1);
        s += __shfl_xor(s, 2);
        s += __shfl_xor(s, 4);
        s += __shfl_xor(s, 8);
        if (r == 0) atomicAdd(&ssq[sbase + b * 32 + oc], s);
      }
    }
  }
}

// ---------------- kernel 2: in-place scale of Q,K ----------------
__global__ void scale_kernel(unsigned int* __restrict__ qw, unsigned int* __restrict__ kw,
                             const float* __restrict__ ssq, const float* __restrict__ temp) {
  int tt = blockIdx.x * 256 + threadIdx.x;   // 1,048,576 u32 total (q then k)
  int is_k = tt >> 19;
  int idx = tt & 0x7FFFF;
  unsigned int* ptr = is_k ? kw : qw;
  unsigned int v = ptr[idx];
  int c0 = (idx & 15) * 2;
  int b = idx >> 16;
  float invt = is_k ? 1.0f : 1.0f / (temp[0] + 1e-6f);
  float s0 = ssq[is_k * 256 + b * 32 + c0];
  float s1 = ssq[is_k * 256 + b * 32 + c0 + 1];
  float sc0 = invt / fmaxf(sqrtf(s0), 1e-12f);
  float sc1 = invt / fmaxf(sqrtf(s1), 1e-12f);
  unsigned short lo = f2bf(bf2f((unsigned short)(v & 0xFFFFu)) * sc0);
  unsigned short hi = f2bf(bf2f((unsigned short)(v >> 16)) * sc1);
  ptr[idx] = ((unsigned int)hi << 16) | lo;
}

// ---------------- kernel 3: 2-pass flash attention ----------------
// block = 4 waves, 64 query rows (m). wave w owns m-tile w for S/softmax/P,
// and cv-slice [w*64, w*64+64) for PV. S^T = mfma(K, Q): lane column m = lane&15.
__launch_bounds__(256, 2)
__global__ void attn_kernel(const unsigned short* __restrict__ qbf,
                            const unsigned short* __restrict__ kbf,
                            const unsigned short* __restrict__ vbf,
                            const float* __restrict__ x, const float* __restrict__ gamma,
                            float* __restrict__ out) {
  __shared__ unsigned short Plds[4][16][72];   // [m-tile][m][n(64) pad to 72]
  int b = blockIdx.x & 7, mblk = blockIdx.x >> 3;
  int w = threadIdx.x >> 6, lane = threadIdx.x & 63;
  int r = lane & 15, g = lane >> 4;
  const unsigned short* qb = qbf + (size_t)b * N_ * 32;
  const unsigned short* kb = kbf + (size_t)b * N_ * 32;
  const unsigned short* vb = vbf + (size_t)b * C_ * N_;
  int m0 = mblk * 64 + w * 16;
  short8 qfrag = *(const short8*)&qb[(m0 + r) * 32 + g * 8];
  floatx4 zero = {0.f, 0.f, 0.f, 0.f};

  // ---- pass 1: exact row max M and denom L (per-lane partial state) ----
  float M = -INFINITY, L = 0.0f;
  #pragma unroll 1
  for (int nt = 0; nt < 64; ++nt) {
    int nbase = nt * 64;
    floatx4 s[4];
    #pragma unroll
    for (int f = 0; f < 4; ++f) {
      short8 kf = *(const short8*)&kb[(size_t)(nbase + f * 16 + r) * 32 + g * 8];
      s[f] = __builtin_amdgcn_mfma_f32_16x16x32_bf16(kf, qfrag, zero, 0, 0, 0);
    }
    if (nt == mblk) {                       // +I on diagonal
      int d = r - 4 * g;
      if (d >= 0 && d < 4) s[w][d] += 1.0f;
    }
    float tmax = -INFINITY;
    #pragma unroll
    for (int f = 0; f < 4; ++f)
      #pragma unroll
      for (int rr = 0; rr < 4; ++rr) tmax = fmaxf(tmax, s[f][rr]);
    float newM = fmaxf(M, tmax);
    float tsum = 0.f;
    #pragma unroll
    for (int f = 0; f < 4; ++f)
      #pragma unroll
      for (int rr = 0; rr < 4; ++rr) tsum += __expf(s[f][rr] - newM);
    L = L * __expf(M - newM) + tsum;
    M = newM;
  }
  // combine the 4 g-partials of column m
  #pragma unroll
  for (int mask = 16; mask <= 32; mask <<= 1) {
    float Mo = __shfl_xor(M, mask);
    float Lo = __shfl_xor(L, mask);
    float Mn = fmaxf(M, Mo);
    L = L * __expf(M - Mn) + Lo * __expf(Mo - Mn);
    M = Mn;
  }
  float linv = 1.0f / L;

  // ---- pass 2: P = exp(S-M)/L, O^T += V * P^T (cv-split across waves) ----
  floatx4 acc[4][4];
  #pragma unroll
  for (int mt = 0; mt < 4; ++mt)
    #pragma unroll
    for (int ct = 0; ct < 4; ++ct) acc[mt][ct] = zero;
  int cvbase = w * 64;

  #pragma unroll 1
  for (int nt = 0; nt < 64; ++nt) {
    int nbase = nt * 64;
    floatx4 s[4];
    #pragma unroll
    for (int f = 0; f < 4; ++f) {
      short8 kf = *(const short8*)&kb[(size_t)(nbase + f * 16 + r) * 32 + g * 8];
      s[f] = __builtin_amdgcn_mfma_f32_16x16x32_bf16(kf, qfrag, zero, 0, 0, 0);
    }
    if (nt == mblk) {
      int d = r - 4 * g;
      if (d >= 0 && d < 4) s[w][d] += 1.0f;
    }
    #pragma unroll
    for (int f = 0; f < 4; ++f) {
      float p0 = __expf(s[f][0] - M) * linv;
      float p1 = __expf(s[f][1] - M) * linv;
      float p2 = __expf(s[f][2] - M) * linv;
      float p3 = __expf(s[f][3] - M) * linv;
      unsigned int u01 = ((unsigned int)f2bf(p1) << 16) | f2bf(p0);
      unsigned int u23 = ((unsigned int)f2bf(p3) << 16) | f2bf(p2);
      *(unsigned int*)&Plds[w][r][f * 16 + 4 * g] = u01;
      *(unsigned int*)&Plds[w][r][f * 16 + 4 * g + 2] = u23;
    }
    // V fragments straight from global (L2-resident, XCD-affine batch)
    short8 vf[2][4];
    #pragma unroll
    for (int ks = 0; ks < 2; ++ks)
      #pragma unroll
      for (int ct = 0; ct < 4; ++ct)
        vf[ks][ct] = *(const short8*)&vb[(size_t)(cvbase + ct * 16 + r) * N_ + nbase + ks * 32 + g * 8];
    __syncthreads();
    #pragma unroll
    for (int ks = 0; ks < 2; ++ks) {
      short8 pf[4];
      #pragma unroll
      for (int mt = 0; mt < 4; ++mt)
        pf[mt] = *(const short8*)&Plds[mt][r][ks * 32 + g * 8];
      #pragma unroll
      for (int ct = 0; ct < 4; ++ct)
        #pragma unroll
        for (int mt = 0; mt < 4; ++mt)
          acc[mt][ct] = __builtin_amdgcn_mfma_f32_16x16x32_bf16(vf[ks][ct], pf[mt], acc[mt][ct], 0, 0, 0);
    }
    __syncthreads();
  }

  // ---- epilogue: out = gamma * O + x ----
  float gam = gamma[0];
  #pragma unroll
  for (int mt = 0; mt < 4; ++mt)
    #pragma unroll
    for (int ct = 0; ct < 4; ++ct)
      #pragma unroll
      for (int rr = 0; rr < 4; ++rr) {
        int cv = cvbase + ct * 16 + g * 4 + rr;
        int m = mblk * 64 + mt * 16 + r;
        size_t idx = ((size_t)(b * C_ + cv) << 12) + m;
        out[idx] = gam * acc[mt][ct][rr] + x[idx];
      }
}

extern "C" void kernel_launch(void* const* d_in, const int* in_sizes, int n_in,
                              void* d_out, int out_size, void* d_ws, size_t ws_size,
                              hipStream_t stream) {
  (void)in_sizes; (void)n_in; (void)out_size; (void)ws_size;
  const float* x    = (const float*)d_in[0];
  const float* Wq   = (const float*)d_in[1];
  const float* bq   = (const float*)d_in[2];
  const float* Wk   = (const float*)d_in[3];
  const float* bk   = (const float*)d_in[4];
  const float* Wv   = (const float*)d_in[5];
  const float* bv   = (const float*)d_in[6];
  const float* gam  = (const float*)d_in[7];
  const float* temp = (const float*)d_in[8];
  float* out = (float*)d_out;

  char* ws = (char*)d_ws;
  unsigned short* vbf = (unsigned short*)ws;                       // 16 MB
  unsigned short* qbf = (unsigned short*)(ws + (16u << 20));       // 2 MB
  unsigned short* kbf = (unsigned short*)(ws + (18u << 20));       // 2 MB
  unsigned short* wqb = (unsigned short*)(ws + (20u << 20));       // 16 KB
  unsigned short* wkb = wqb + 8192;                                // 16 KB
  unsigned short* wvb = wkb + 8192;                                // 128 KB
  float* ssq = (float*)(wvb + 65536);                              // 2 KB

  prep_kernel<<<dim3(288), dim3(256), 0, stream>>>(Wq, Wk, Wv, wqb, wkb, wvb, ssq);
  qkv_kernel<<<dim3(512), dim3(256), 0, stream>>>(x, wqb, wkb, wvb, bq, bk, bv, qbf, kbf, vbf, ssq);
  scale_kernel<<<dim3(4096), dim3(256), 0, stream>>>((unsigned int*)qbf, (unsigned int*)kbf, ssq, temp);
  attn_kernel<<<dim3(512), dim3(256), 0, stream>>>(qbf, kbf, vbf, x, gam, out);
}

// Round 2
// 243.734 us; speedup vs baseline: 1.2372x; 1.2372x over previous
//
#include <hip/hip_runtime.h>
#include <hip/hip_bf16.h>
#include <math.h>

typedef __attribute__((ext_vector_type(8))) short short8;
typedef __attribute__((ext_vector_type(4))) float floatx4;

#define B_ 8
#define C_ 256
#define N_ 4096

static __device__ __forceinline__ unsigned short f2bf(float f) {
  union { float f; unsigned int u; } v; v.f = f;
  unsigned int u = v.u;
  u += 0x7FFFu + ((u >> 16) & 1u);   // RNE
  return (unsigned short)(u >> 16);
}
static __device__ __forceinline__ float bf2f(unsigned short h) {
  union { unsigned int u; float f; } v; v.u = ((unsigned int)h) << 16; return v.f;
}

// ---------------- kernel 0: weight convert + ssq zero ----------------
__global__ void prep_kernel(const float* __restrict__ Wq, const float* __restrict__ Wk,
                            const float* __restrict__ Wv,
                            unsigned short* __restrict__ wqb, unsigned short* __restrict__ wkb,
                            unsigned short* __restrict__ wvb, float* __restrict__ ssq) {
  int t = blockIdx.x * 256 + threadIdx.x;
  if (t < 512) ssq[t] = 0.0f;
  if (t < 8192) { wqb[t] = f2bf(Wq[t]); wkb[t] = f2bf(Wk[t]); }
  int tv = t - 8192;
  if (tv >= 0 && tv < 65536) wvb[tv] = f2bf(Wv[tv]);
}

// ---------------- kernel 1: QKV GEMM (bf16 MFMA) ----------------
// out tiles: V (b,c,n) bf16 ; Q/K unscaled (b,n,32) bf16 ; ssq atomics
__launch_bounds__(256, 2)
__global__ void qkv_kernel(const float* __restrict__ x,
                           const unsigned short* __restrict__ wqb,
                           const unsigned short* __restrict__ wkb,
                           const unsigned short* __restrict__ wvb,
                           const float* __restrict__ bq, const float* __restrict__ bk,
                           const float* __restrict__ bv,
                           unsigned short* __restrict__ qbf, unsigned short* __restrict__ kbf,
                           unsigned short* __restrict__ vbf, float* __restrict__ ssq) {
  int b = blockIdx.x >> 6;
  int nblk = blockIdx.x & 63;
  int w = threadIdx.x >> 6, lane = threadIdx.x & 63;
  int r = lane & 15, g = lane >> 4;
  int n0 = nblk * 64 + w * 16;

  // B fragments from x: B[k=c][col=n], lane: col=r, k = g*8+j (per 32-k step)
  short8 xf[8];
  #pragma unroll
  for (int ks = 0; ks < 8; ++ks) {
    #pragma unroll
    for (int j = 0; j < 8; ++j) {
      int c = ks * 32 + g * 8 + j;
      float v = x[((size_t)(b * C_ + c) << 12) + n0 + r];
      ((unsigned short*)&xf[ks])[j] = f2bf(v);
    }
  }
  floatx4 zero = {0.f, 0.f, 0.f, 0.f};

  // ---- V tiles (16 of them) ----
  #pragma unroll 1
  for (int ot = 0; ot < 16; ++ot) {
    floatx4 acc = zero;
    #pragma unroll
    for (int ks = 0; ks < 8; ++ks) {
      short8 af = *(const short8*)&wvb[(ot * 16 + r) * 256 + ks * 32 + g * 8];
      acc = __builtin_amdgcn_mfma_f32_16x16x32_bf16(af, xf[ks], acc, 0, 0, 0);
    }
    #pragma unroll
    for (int rr = 0; rr < 4; ++rr) {
      int oc = ot * 16 + g * 4 + rr;
      vbf[((size_t)(b * C_ + oc) << 12) + n0 + r] = f2bf(acc[rr] + bv[oc]);
    }
  }
  // ---- Q then K (2 tiles each) ----
  #pragma unroll 1
  for (int qk = 0; qk < 2; ++qk) {
    const unsigned short* wb = qk ? wkb : wqb;
    const float* bias = qk ? bk : bq;
    unsigned short* dst = qk ? kbf : qbf;
    int sbase = qk ? 256 : 0;
    #pragma unroll
    for (int ot = 0; ot < 2; ++ot) {
      floatx4 acc = zero;
      #pragma unroll
      for (int ks = 0; ks < 8; ++ks) {
        short8 af = *(const short8*)&wb[(ot * 16 + r) * 256 + ks * 32 + g * 8];
        acc = __builtin_amdgcn_mfma_f32_16x16x32_bf16(af, xf[ks], acc, 0, 0, 0);
      }
      #pragma unroll
      for (int rr = 0; rr < 4; ++rr) {
        int oc = ot * 16 + g * 4 + rr;
        float val = acc[rr] + bias[oc];
        dst[(size_t)(b * N_ + n0 + r) * 32 + oc] = f2bf(val);
        float s = val * val;               // reduce over the 16 n (lanes r)
        s += __shfl_xor(s, 1);
        s += __shfl_xor(s, 2);
        s += __shfl_xor(s, 4);
        s += __shfl_xor(s, 8);
        if (r == 0) atomicAdd(&ssq[sbase + b * 32 + oc], s);
      }
    }
  }
}

// ---------------- kernel 2: in-place scale of Q,K ----------------
__global__ void scale_kernel(unsigned int* __restrict__ qw, unsigned int* __restrict__ kw,
                             const float* __restrict__ ssq, const float* __restrict__ temp) {
  int tt = blockIdx.x * 256 + threadIdx.x;   // 1,048,576 u32 total (q then k)
  int is_k = tt >> 19;
  int idx = tt & 0x7FFFF;
  unsigned int* ptr = is_k ? kw : qw;
  unsigned int v = ptr[idx];
  int c0 = (idx & 15) * 2;
  int b = idx >> 16;
  float invt = is_k ? 1.0f : 1.0f / (temp[0] + 1e-6f);
  float s0 = ssq[is_k * 256 + b * 32 + c0];
  float s1 = ssq[is_k * 256 + b * 32 + c0 + 1];
  float sc0 = invt / fmaxf(sqrtf(s0), 1e-12f);
  float sc1 = invt / fmaxf(sqrtf(s1), 1e-12f);
  unsigned short lo = f2bf(bf2f((unsigned short)(v & 0xFFFFu)) * sc0);
  unsigned short hi = f2bf(bf2f((unsigned short)(v >> 16)) * sc1);
  ptr[idx] = ((unsigned int)hi << 16) | lo;
}

// ---------------- kernel 3: ONE-pass attention, constant shift ----------------
// |S| = |q_hat . k_hat| / (1+1e-6) <= 1.0001 (L2-normalized), +1 on diag -> S <= 2.0001.
// Softmax is shift-invariant -> use constant shift M=2: P = exp(S-2) in [e^-3, 1].
// No max tracking, no rescale, single pass. P double-buffered in LDS -> ONE barrier/iter.
// K and V fragments register-prefetched one n-tile ahead (L2-resident per XCD via b=blockIdx&7).
__launch_bounds__(256, 2)
__global__ void attn_kernel(const unsigned short* __restrict__ qbf,
                            const unsigned short* __restrict__ kbf,
                            const unsigned short* __restrict__ vbf,
                            const float* __restrict__ x, const float* __restrict__ gamma,
                            float* __restrict__ out) {
  __shared__ unsigned short Plds[2][4][16][72];   // [buf][m-tile][m][n(64) pad 72]
  __shared__ float Lbc[64];
  int b = blockIdx.x & 7, mblk = blockIdx.x >> 3;
  int w = threadIdx.x >> 6, lane = threadIdx.x & 63;
  int r = lane & 15, g = lane >> 4;
  const unsigned short* qb = qbf + (size_t)b * N_ * 32;
  const unsigned short* kb = kbf + (size_t)b * N_ * 32;
  const unsigned short* vb = vbf + (size_t)b * C_ * N_;
  int m0 = mblk * 64 + w * 16;
  int cvbase = w * 64;
  short8 qfrag = *(const short8*)&qb[(m0 + r) * 32 + g * 8];
  floatx4 zero = {0.f, 0.f, 0.f, 0.f};

  floatx4 acc[4][4];                              // [mt][ct] O^T accum (unnormalized)
  #pragma unroll
  for (int mt = 0; mt < 4; ++mt)
    #pragma unroll
    for (int ct = 0; ct < 4; ++ct) acc[mt][ct] = zero;
  float Lp = 0.0f;

  // preload K,V fragments for nt=0
  short8 kf[4], vfA[2][4], vfB[2][4];
  #pragma unroll
  for (int f = 0; f < 4; ++f)
    kf[f] = *(const short8*)&kb[(size_t)(f * 16 + r) * 32 + g * 8];
  #pragma unroll
  for (int ks = 0; ks < 2; ++ks)
    #pragma unroll
    for (int ct = 0; ct < 4; ++ct)
      vfA[ks][ct] = *(const short8*)&vb[(size_t)(cvbase + ct * 16 + r) * N_ + ks * 32 + g * 8];

  auto body = [&](int nt, short8 (&vcur)[2][4], short8 (&vnxt)[2][4]) {
    int pb = nt & 1;
    int nb2 = ((nt + 1) & 63) * 64;               // wrap: last iter reloads tile 0 (unused)
    floatx4 s[4];
    #pragma unroll
    for (int f = 0; f < 4; ++f)
      s[f] = __builtin_amdgcn_mfma_f32_16x16x32_bf16(kf[f], qfrag, zero, 0, 0, 0);
    // K prefetch for nt+1 (kf dead after the MFMAs above)
    #pragma unroll
    for (int f = 0; f < 4; ++f)
      kf[f] = *(const short8*)&kb[(size_t)(nb2 + f * 16 + r) * 32 + g * 8];
    if (nt == mblk) {                             // +I on the diagonal
      int d = r - 4 * g;
      if (d >= 0 && d < 4) s[w][d] += 1.0f;
    }
    // P = exp(S-2), accumulate L, pack bf16 -> LDS (one b64 write per f)
    #pragma unroll
    for (int f = 0; f < 4; ++f) {
      float p0 = __expf(s[f][0] - 2.0f);
      float p1 = __expf(s[f][1] - 2.0f);
      float p2 = __expf(s[f][2] - 2.0f);
      float p3 = __expf(s[f][3] - 2.0f);
      Lp += (p0 + p1) + (p2 + p3);
      uint2 uu;
      uu.x = ((unsigned int)f2bf(p1) << 16) | f2bf(p0);
      uu.y = ((unsigned int)f2bf(p3) << 16) | f2bf(p2);
      *(uint2*)&Plds[pb][w][r][f * 16 + 4 * g] = uu;
    }
    // V prefetch for nt+1 — issued before the barrier so latency hides under exp/pack
    #pragma unroll
    for (int ks = 0; ks < 2; ++ks)
      #pragma unroll
      for (int ct = 0; ct < 4; ++ct)
        vnxt[ks][ct] = *(const short8*)&vb[(size_t)(cvbase + ct * 16 + r) * N_ + nb2 + ks * 32 + g * 8];
    __syncthreads();                              // P[pb] visible to all waves
    #pragma unroll
    for (int ks = 0; ks < 2; ++ks) {
      short8 pf[4];
      #pragma unroll
      for (int mt = 0; mt < 4; ++mt)
        pf[mt] = *(const short8*)&Plds[pb][mt][r][ks * 32 + g * 8];
      #pragma unroll
      for (int ct = 0; ct < 4; ++ct)
        #pragma unroll
        for (int mt = 0; mt < 4; ++mt)
          acc[mt][ct] = __builtin_amdgcn_mfma_f32_16x16x32_bf16(vcur[ks][ct], pf[mt], acc[mt][ct], 0, 0, 0);
    }
  };
  #pragma unroll 1
  for (int nt = 0; nt < 64; nt += 2) { body(nt, vfA, vfB); body(nt + 1, vfB, vfA); }

  // column denominators: combine g-partials, broadcast via LDS
  Lp += __shfl_xor(Lp, 16);
  Lp += __shfl_xor(Lp, 32);
  if (g == 0) Lbc[w * 16 + r] = Lp;
  __syncthreads();
  float linv[4];
  #pragma unroll
  for (int mt = 0; mt < 4; ++mt) linv[mt] = 1.0f / Lbc[mt * 16 + r];

  // epilogue: out = gamma * (O/L) + x
  float gam = gamma[0];
  #pragma unroll
  for (int mt = 0; mt < 4; ++mt)
    #pragma unroll
    for (int ct = 0; ct < 4; ++ct)
      #pragma unroll
      for (int rr = 0; rr < 4; ++rr) {
        int cv = cvbase + ct * 16 + g * 4 + rr;
        int m = mblk * 64 + mt * 16 + r;
        size_t idx = ((size_t)(b * C_ + cv) << 12) + m;
        out[idx] = gam * acc[mt][ct][rr] * linv[mt] + x[idx];
      }
}

extern "C" void kernel_launch(void* const* d_in, const int* in_sizes, int n_in,
                              void* d_out, int out_size, void* d_ws, size_t ws_size,
                              hipStream_t stream) {
  (void)in_sizes; (void)n_in; (void)out_size; (void)ws_size;
  const float* x    = (const float*)d_in[0];
  const float* Wq   = (const float*)d_in[1];
  const float* bq   = (const float*)d_in[2];
  const float* Wk   = (const float*)d_in[3];
  const float* bk   = (const float*)d_in[4];
  const float* Wv   = (const float*)d_in[5];
  const float* bv   = (const float*)d_in[6];
  const float* gam  = (const float*)d_in[7];
  const float* temp = (const float*)d_in[8];
  float* out = (float*)d_out;

  char* ws = (char*)d_ws;
  unsigned short* vbf = (unsigned short*)ws;                       // 16 MB
  unsigned short* qbf = (unsigned short*)(ws + (16u << 20));       // 2 MB
  unsigned short* kbf = (unsigned short*)(ws + (18u << 20));       // 2 MB
  unsigned short* wqb = (unsigned short*)(ws + (20u << 20));       // 16 KB
  unsigned short* wkb = wqb + 8192;                                // 16 KB
  unsigned short* wvb = wkb + 8192;                                // 128 KB
  float* ssq = (float*)(wvb + 65536);                              // 2 KB

  prep_kernel<<<dim3(288), dim3(256), 0, stream>>>(Wq, Wk, Wv, wqb, wkb, wvb, ssq);
  qkv_kernel<<<dim3(512), dim3(256), 0, stream>>>(x, wqb, wkb, wvb, bq, bk, bv, qbf, kbf, vbf, ssq);
  scale_kernel<<<dim3(4096), dim3(256), 0, stream>>>((unsigned int*)qbf, (unsigned int*)kbf, ssq, temp);
  attn_kernel<<<dim3(512), dim3(256), 0, stream>>>(qbf, kbf, vbf, x, gam, out);
}